// Round 1
// baseline (51.939 us; speedup 1.0000x reference)
//
#include <hip/hip_runtime.h>

#define NCLS 64 + 16   // 80 classes
#define ROWF 84        // floats per output row (80 cls + 4 reg)

// One block = 64 consecutive points of one image. Each thread owns one point
// and a private 84-float LDS row (cls scatter-max target + output staging).
__global__ __launch_bounds__(64) void lfd_assign_kernel(
    const float* __restrict__ gt_bboxes,   // (B,G,4) x0,y0,w,h
    const int*   __restrict__ gt_labels,   // (B,G)
    const float* __restrict__ points,      // (P,2)
    const float* __restrict__ reg_ranges,  // (P,2)
    const float* __restrict__ gray_ranges, // (P,2)
    const float* __restrict__ strides,     // (P,)
    float* __restrict__ out,               // (B,P,84)
    int G, int P)
{
    extern __shared__ float lds[];
    float* rows = lds;                 // 64 * 84 floats
    float* gt   = lds + 64 * ROWF;     // G * 8 floats: x0,y0,x1m1,y1m1,cx,cy,larger,label

    const int tid = threadIdx.x;
    const int b   = blockIdx.y;
    const int p   = blockIdx.x * 64 + tid;

    // --- preload & precompute gt data into LDS ---
    for (int g = tid; g < G; g += 64) {
        const float4 bb = *reinterpret_cast<const float4*>(gt_bboxes + (size_t)(b * G + g) * 4);
        const float x0 = bb.x, y0 = bb.y, w = bb.z, h = bb.w;
        gt[g * 8 + 0] = x0;
        gt[g * 8 + 1] = y0;
        gt[g * 8 + 2] = x0 + w - 1.0f;       // x1m1
        gt[g * 8 + 3] = y0 + h - 1.0f;       // y1m1
        gt[g * 8 + 4] = x0 + 0.5f * w;       // cx
        gt[g * 8 + 5] = y0 + 0.5f * h;       // cy
        gt[g * 8 + 6] = fmaxf(w, h);         // larger
        reinterpret_cast<int*>(gt)[g * 8 + 7] = gt_labels[b * G + g];
    }

    // --- zero my private row (cls init = 0) ---
    float* myrow = rows + tid * ROWF;        // 336 B stride, 16B-aligned
#pragma unroll
    for (int k = 0; k < 21; ++k)
        *reinterpret_cast<float4*>(myrow + 4 * k) = make_float4(0.f, 0.f, 0.f, 0.f);

    __syncthreads();

    // --- per-point (block-uniform level) constants ---
    const float px = points[p * 2 + 0];
    const float py = points[p * 2 + 1];
    const float lo  = reg_ranges[p * 2 + 0];
    const float up  = reg_ranges[p * 2 + 1];
    const float glo = gray_ranges[p * 2 + 0];
    const float gup = gray_ranges[p * 2 + 1];
    const float inv_half = 2.0f / strides[p];  // strides are pow2 -> exact
    const float inv_up   = 1.0f / up;

    float best_score = 0.0f; int best_g = 0;   // argmax score among green (strict > => smallest g on ties)
    float min_score  = 1e30f; int min_g = 0;   // argmin score over all g  (strict < => smallest g on ties)
    unsigned gm0 = 0u, gm1 = 0u, gm2 = 0u;     // gray label bitmask (80 bits)

    for (int g = 0; g < G; ++g) {
        const float4 B2 = *reinterpret_cast<const float4*>(gt + g * 8 + 4); // cx,cy,larger,label
        const float cx = B2.x, cy = B2.y, larger = B2.z;

        const float xs = fmaxf(fabsf(px - cx) * inv_half, 1.0f);
        const float ys = fmaxf(fabsf(py - cy) * inv_half, 1.0f);
        const float score = rsqrtf(xs * ys);   // = sqrt(1/xs)*sqrt(1/ys), xs*ys in [1, ~2.5e5]

        if (score < min_score) { min_score = score; min_g = g; }

        // wave-uniform size-range checks (lo/up/glo/gup uniform in block; larger uniform in g)
        const bool sizeGreen = (lo <= larger) && (larger <= up);
        const bool sizeGray  = ((glo <= larger) && (larger < lo)) ||
                               ((up < larger) && (larger <= gup));
        if (sizeGreen || sizeGray) {
            const float4 A = *reinterpret_cast<const float4*>(gt + g * 8); // x0,y0,x1m1,y1m1
            const float d1 = px - A.x, d2 = py - A.y, d3 = A.z - px, d4 = A.w - py;
            const bool hit = fminf(fminf(d1, d2), fminf(d3, d4)) >= 0.0f;
            if (hit) {
                const int label = reinterpret_cast<const int*>(gt)[g * 8 + 7];
                if (sizeGreen) {
                    const float cur = myrow[label];
                    if (score > cur) myrow[label] = score;
                    if (score > best_score) { best_score = score; best_g = g; }
                } else {
                    const unsigned m = 1u << (label & 31);
                    if (label < 32)      gm0 |= m;
                    else if (label < 64) gm1 |= m;
                    else                 gm2 |= m;
                }
            }
        }
    }

    // --- gray override: cls[c] = -1 wherever any gray gt had label c ---
    while (gm0) { const int c = __ffs(gm0) - 1; myrow[c]      = -1.0f; gm0 &= gm0 - 1u; }
    while (gm1) { const int c = __ffs(gm1) - 1; myrow[32 + c] = -1.0f; gm1 &= gm1 - 1u; }
    while (gm2) { const int c = __ffs(gm2) - 1; myrow[64 + c] = -1.0f; gm2 &= gm2 - 1u; }

    // --- reg output: best green candidate, else global min-score gt ---
    const int sel = (best_score > 0.0f) ? best_g : min_g;
    const float4 A = *reinterpret_cast<const float4*>(gt + sel * 8);
    myrow[80] = (px - A.x) * inv_up;
    myrow[81] = (py - A.y) * inv_up;
    myrow[82] = (A.z - px) * inv_up;
    myrow[83] = (A.w - py) * inv_up;

    __syncthreads();

    // --- coalesced copy: 64 rows * 84 floats = 1344 float4, contiguous ---
    float4* dst = reinterpret_cast<float4*>(out + (size_t)(b * P + blockIdx.x * 64) * ROWF);
    const float4* src = reinterpret_cast<const float4*>(rows);
#pragma unroll
    for (int k = 0; k < 21; ++k)
        dst[k * 64 + tid] = src[k * 64 + tid];
}

extern "C" void kernel_launch(void* const* d_in, const int* in_sizes, int n_in,
                              void* d_out, int out_size, void* d_ws, size_t ws_size,
                              hipStream_t stream) {
    const float* gt_bboxes   = (const float*)d_in[0];
    const int*   gt_labels   = (const int*)d_in[1];
    const float* points      = (const float*)d_in[2];
    const float* reg_ranges  = (const float*)d_in[3];
    const float* gray_ranges = (const float*)d_in[4];
    const float* strides     = (const float*)d_in[5];
    float* out = (float*)d_out;

    const int P  = in_sizes[5];            // strides has P elements
    const int B  = out_size / (P * ROWF);  // out is (B,P,84)
    const int G  = in_sizes[1] / B;        // gt_labels is (B,G)

    dim3 grid(P / 64, B);
    dim3 block(64);
    const size_t shmem = (size_t)(64 * ROWF + G * 8) * sizeof(float);
    lfd_assign_kernel<<<grid, block, shmem, stream>>>(
        gt_bboxes, gt_labels, points, reg_ranges, gray_ranges, strides, out, G, P);
}

// Round 2
// 37.406 us; speedup vs baseline: 1.3885x; 1.3885x over previous
//
#include <hip/hip_runtime.h>

#define ROWF 84        // floats per output row (80 cls + 4 reg)

// One block = 64 consecutive points of one image (one wave). Each thread owns
// one point and a private 84-float LDS row (cls scatter-max + output staging).
// Phase 1: preload gt boxes into LDS + ballot-compact the size-relevant gts
//          (size gate is block-uniform: all 64 points share one FPN level).
// Phase 2: branchless unrolled min-score scan over ALL gts (argmin fallback).
// Phase 3: heavy loop over the compacted list only (hit test, scatter-max,
//          gray mask, best-green argmax). Ascending-g order preserved so
//          strict >/< reproduces stable-sort tie-breaking.
__global__ __launch_bounds__(64) void lfd_assign_kernel(
    const float* __restrict__ gt_bboxes,   // (B,G,4) x0,y0,w,h
    const int*   __restrict__ gt_labels,   // (B,G)
    const float* __restrict__ points,      // (P,2)
    const float* __restrict__ reg_ranges,  // (P,2)
    const float* __restrict__ gray_ranges, // (P,2)
    const float* __restrict__ strides,     // (P,)
    float* __restrict__ out,               // (B,P,84)
    int G, int P)
{
    extern __shared__ float lds[];
    float*    rows  = lds;                            // 64*84 floats
    float4*   boxA  = (float4*)(lds + 64 * ROWF);     // G: x0,y0,x1m1,y1m1
    float2*   ctr   = (float2*)(boxA + G);            // G: cx,cy (16B-aligned base)
    unsigned* clist = (unsigned*)(ctr + ((G + 1) & ~1)); // compacted entries

    const int tid = threadIdx.x;
    const int b   = blockIdx.y;
    const int p   = blockIdx.x * 64 + tid;

    // --- per-point (block-uniform level) constants ---
    const float px  = points[p * 2 + 0];
    const float py  = points[p * 2 + 1];
    const float lo  = reg_ranges[p * 2 + 0];
    const float up  = reg_ranges[p * 2 + 1];
    const float glo = gray_ranges[p * 2 + 0];
    const float gup = gray_ranges[p * 2 + 1];
    const float inv_half = 2.0f / strides[p];  // strides pow2 -> exact
    const float inv_up   = 1.0f / up;

    // --- preload gts (2 slots: g=tid, g=tid+64), classify size-relevance ---
    bool i0 = false, gray0 = false, i1 = false, gray1 = false;
    int  lab0 = 0, lab1 = 0;
    {
        int g = tid;
        if (g < G) {
            const float4 bb = *(const float4*)(gt_bboxes + (size_t)(b * G + g) * 4);
            boxA[g] = make_float4(bb.x, bb.y, bb.x + bb.z - 1.0f, bb.y + bb.w - 1.0f);
            ctr[g]  = make_float2(bb.x + 0.5f * bb.z, bb.y + 0.5f * bb.w);
            const float larger = fmaxf(bb.z, bb.w);
            lab0 = gt_labels[b * G + g];
            const bool green = (lo <= larger) && (larger <= up);
            gray0 = ((glo <= larger) && (larger < lo)) || ((up < larger) && (larger <= gup));
            i0 = green || gray0;
        }
        g = tid + 64;
        if (g < G) {
            const float4 bb = *(const float4*)(gt_bboxes + (size_t)(b * G + g) * 4);
            boxA[g] = make_float4(bb.x, bb.y, bb.x + bb.z - 1.0f, bb.y + bb.w - 1.0f);
            ctr[g]  = make_float2(bb.x + 0.5f * bb.z, bb.y + 0.5f * bb.w);
            const float larger = fmaxf(bb.z, bb.w);
            lab1 = gt_labels[b * G + g];
            const bool green = (lo <= larger) && (larger <= up);
            gray1 = ((glo <= larger) && (larger < lo)) || ((up < larger) && (larger <= gup));
            i1 = green || gray1;
        }
    }
    // ballot-compaction (single wave; ascending-g order preserved)
    const unsigned long long m0 = __ballot(i0);
    const unsigned long long m1 = __ballot(i1);
    const int c0 = __popcll(m0);
    const unsigned long long below = (1ull << tid) - 1ull;
    if (i0) clist[__popcll(m0 & below)] =
        (unsigned)tid | ((unsigned)lab0 << 8) | (gray0 ? 0x80000000u : 0u);
    if (i1) clist[c0 + __popcll(m1 & below)] =
        (unsigned)(tid + 64) | ((unsigned)lab1 << 8) | (gray1 ? 0x80000000u : 0u);
    const int ncomp = c0 + __popcll(m1);

    // --- zero my private row ---
    float* myrow = rows + tid * ROWF;  // 336B stride, 16B-aligned
#pragma unroll
    for (int k = 0; k < 21; ++k)
        *reinterpret_cast<float4*>(myrow + 4 * k) = make_float4(0.f, 0.f, 0.f, 0.f);

    __syncthreads();

    // --- phase 2: branchless min-score scan over ALL gts (2 gts per b128) ---
    const float4* ctr2 = (const float4*)ctr;
    float min_score = 1e30f; int min_g = 0;
    int g = 0;
#pragma unroll 4
    for (; g + 1 < G; g += 2) {
        const float4 c = ctr2[g >> 1];
        const float s0 = rsqrtf(fmaxf(fabsf(px - c.x) * inv_half, 1.0f) *
                                fmaxf(fabsf(py - c.y) * inv_half, 1.0f));
        const float s1 = rsqrtf(fmaxf(fabsf(px - c.z) * inv_half, 1.0f) *
                                fmaxf(fabsf(py - c.w) * inv_half, 1.0f));
        if (s0 < min_score) { min_score = s0; min_g = g; }
        if (s1 < min_score) { min_score = s1; min_g = g + 1; }
    }
    if (g < G) {
        const float2 c = ctr[g];
        const float s0 = rsqrtf(fmaxf(fabsf(px - c.x) * inv_half, 1.0f) *
                                fmaxf(fabsf(py - c.y) * inv_half, 1.0f));
        if (s0 < min_score) { min_score = s0; min_g = g; }
    }

    // --- phase 3: heavy loop over compacted (size-relevant) gts only ---
    float best_score = 0.0f; int best_g = 0;
    unsigned gm0 = 0u, gm1 = 0u, gm2 = 0u;
    for (int i = 0; i < ncomp; ++i) {
        const unsigned e = clist[i];
        const int gg = (int)(e & 0xFFu);
        const float4 A = boxA[gg];
        const float d1 = px - A.x, d2 = py - A.y, d3 = A.z - px, d4 = A.w - py;
        if (fminf(fminf(d1, d2), fminf(d3, d4)) >= 0.0f) {
            const int label = (int)((e >> 8) & 0x7Fu);
            if (e & 0x80000000u) {          // gray (uniform branch)
                if (label < 32)      gm0 |= 1u << label;
                else if (label < 64) gm1 |= 1u << (label - 32);
                else                 gm2 |= 1u << (label - 64);
            } else {                         // green
                const float2 c = ctr[gg];
                const float s = rsqrtf(fmaxf(fabsf(px - c.x) * inv_half, 1.0f) *
                                       fmaxf(fabsf(py - c.y) * inv_half, 1.0f));
                if (s > myrow[label]) myrow[label] = s;
                if (s > best_score) { best_score = s; best_g = gg; }
            }
        }
    }

    // --- gray override ---
    while (gm0) { const int c = __ffs(gm0) - 1; myrow[c]      = -1.0f; gm0 &= gm0 - 1u; }
    while (gm1) { const int c = __ffs(gm1) - 1; myrow[32 + c] = -1.0f; gm1 &= gm1 - 1u; }
    while (gm2) { const int c = __ffs(gm2) - 1; myrow[64 + c] = -1.0f; gm2 &= gm2 - 1u; }

    // --- reg output: best green, else global min-score gt ---
    const int sel = (best_score > 0.0f) ? best_g : min_g;
    const float4 A = boxA[sel];
    myrow[80] = (px - A.x) * inv_up;
    myrow[81] = (py - A.y) * inv_up;
    myrow[82] = (A.z - px) * inv_up;
    myrow[83] = (A.w - py) * inv_up;

    __syncthreads();

    // --- coalesced copy: 64 rows * 84 floats = 1344 float4, contiguous ---
    float4* dst = reinterpret_cast<float4*>(out + (size_t)(b * P + blockIdx.x * 64) * ROWF);
    const float4* src = reinterpret_cast<const float4*>(rows);
#pragma unroll
    for (int k = 0; k < 21; ++k)
        dst[k * 64 + tid] = src[k * 64 + tid];
}

extern "C" void kernel_launch(void* const* d_in, const int* in_sizes, int n_in,
                              void* d_out, int out_size, void* d_ws, size_t ws_size,
                              hipStream_t stream) {
    const float* gt_bboxes   = (const float*)d_in[0];
    const int*   gt_labels   = (const int*)d_in[1];
    const float* points      = (const float*)d_in[2];
    const float* reg_ranges  = (const float*)d_in[3];
    const float* gray_ranges = (const float*)d_in[4];
    const float* strides     = (const float*)d_in[5];
    float* out = (float*)d_out;

    const int P = in_sizes[5];            // strides has P elements
    const int B = out_size / (P * ROWF);  // out is (B,P,84)
    const int G = in_sizes[1] / B;        // gt_labels is (B,G)  (G<=128 assumed)

    dim3 grid(P / 64, B);
    dim3 block(64);
    const size_t shmem = (size_t)(64 * ROWF) * sizeof(float)
                       + (size_t)G * sizeof(float4)            // boxA
                       + (size_t)((G + 1) & ~1) * sizeof(float2) // ctr (padded)
                       + (size_t)G * sizeof(unsigned);         // clist
    lfd_assign_kernel<<<grid, block, shmem, stream>>>(
        gt_bboxes, gt_labels, points, reg_ranges, gray_ranges, strides, out, G, P);
}

// Round 3
// 33.899 us; speedup vs baseline: 1.5322x; 1.1034x over previous
//
#include <hip/hip_runtime.h>

#define ROWF 84        // floats per output row (80 cls + 4 reg)

// One block = one wave = 64 consecutive points of one image (levels are
// 64-aligned so the wave is level-uniform).
//  Phase 0: preload gt boxes into LDS; ballot-compact size-relevant gts
//           (ascending-g order preserved -> stable-sort tie semantics).
//  Phase 1: bulk-zero this block's 64x84-float output region (coalesced
//           float4 stores; cls is ~99.97% zeros).
//  Phase 2: branchless min-score scan over ALL gts (argmin fallback for reg),
//           overlapping the zero-store drain.
//  fence vmcnt(0)
//  Phase 3: per compacted gt: hit test; green -> atomicMax(out[p][label])
//           (positive-float bits, commutative) + best-green tracking.
//  fence vmcnt(0)
//  Phase 4: gray -1 overrides (plain stores), reg float4 store. All patches
//           to row p come from thread p only -> no cross-thread hazards.
__global__ __launch_bounds__(64) void lfd_assign_kernel(
    const float* __restrict__ gt_bboxes,   // (B,G,4) x0,y0,w,h
    const int*   __restrict__ gt_labels,   // (B,G)
    const float* __restrict__ points,      // (P,2)
    const float* __restrict__ reg_ranges,  // (P,2)
    const float* __restrict__ gray_ranges, // (P,2)
    const float* __restrict__ strides,     // (P,)
    float* __restrict__ out,               // (B,P,84)
    int G, int P)
{
    extern __shared__ float lds[];
    float4*   boxA  = (float4*)lds;                   // G: x0,y0,x1m1,y1m1
    float2*   ctr   = (float2*)(boxA + G);            // G: cx,cy (16B-aligned)
    unsigned* clist = (unsigned*)(ctr + ((G + 1) & ~1));

    const int tid = threadIdx.x;
    const int b   = blockIdx.y;
    const int p   = blockIdx.x * 64 + tid;

    // --- per-point (wave-uniform level) constants ---
    const float px  = points[p * 2 + 0];
    const float py  = points[p * 2 + 1];
    const float lo  = reg_ranges[p * 2 + 0];
    const float up  = reg_ranges[p * 2 + 1];
    const float glo = gray_ranges[p * 2 + 0];
    const float gup = gray_ranges[p * 2 + 1];
    const float inv_half = 2.0f / strides[p];  // strides pow2 -> exact
    const float inv_up   = 1.0f / up;

    // --- phase 0: preload gts (slots g=tid, g=tid+64), classify size ---
    bool i0 = false, gray0 = false, i1 = false, gray1 = false;
    int  lab0 = 0, lab1 = 0;
    {
        int g = tid;
        if (g < G) {
            const float4 bb = *(const float4*)(gt_bboxes + (size_t)(b * G + g) * 4);
            boxA[g] = make_float4(bb.x, bb.y, bb.x + bb.z - 1.0f, bb.y + bb.w - 1.0f);
            ctr[g]  = make_float2(bb.x + 0.5f * bb.z, bb.y + 0.5f * bb.w);
            const float larger = fmaxf(bb.z, bb.w);
            lab0 = gt_labels[b * G + g];
            const bool green = (lo <= larger) && (larger <= up);
            gray0 = ((glo <= larger) && (larger < lo)) || ((up < larger) && (larger <= gup));
            i0 = green || gray0;
        }
        g = tid + 64;
        if (g < G) {
            const float4 bb = *(const float4*)(gt_bboxes + (size_t)(b * G + g) * 4);
            boxA[g] = make_float4(bb.x, bb.y, bb.x + bb.z - 1.0f, bb.y + bb.w - 1.0f);
            ctr[g]  = make_float2(bb.x + 0.5f * bb.z, bb.y + 0.5f * bb.w);
            const float larger = fmaxf(bb.z, bb.w);
            lab1 = gt_labels[b * G + g];
            const bool green = (lo <= larger) && (larger <= up);
            gray1 = ((glo <= larger) && (larger < lo)) || ((up < larger) && (larger <= gup));
            i1 = green || gray1;
        }
    }
    // ballot-compaction (single wave; ascending-g order preserved)
    const unsigned long long m0 = __ballot(i0);
    const unsigned long long m1 = __ballot(i1);
    const int c0 = __popcll(m0);
    const unsigned long long below = (1ull << tid) - 1ull;
    if (i0) clist[__popcll(m0 & below)] =
        (unsigned)tid | ((unsigned)lab0 << 8) | (gray0 ? 0x80000000u : 0u);
    if (i1) clist[c0 + __popcll(m1 & below)] =
        (unsigned)(tid + 64) | ((unsigned)lab1 << 8) | (gray1 ? 0x80000000u : 0u);
    const int ncomp = c0 + __popcll(m1);

    // --- phase 1: bulk-zero the block's output region (fire-and-forget) ---
    float4* dst4 = (float4*)(out + (size_t)(b * P + blockIdx.x * 64) * ROWF);
    const float4 z4 = make_float4(0.f, 0.f, 0.f, 0.f);
#pragma unroll
    for (int k = 0; k < 21; ++k)
        dst4[k * 64 + tid] = z4;

    // --- phase 2: branchless min-score scan over ALL gts (2 per b128) ---
    const float4* ctr2 = (const float4*)ctr;
    float min_score = 1e30f; int min_g = 0;
    int g = 0;
#pragma unroll 4
    for (; g + 1 < G; g += 2) {
        const float4 c = ctr2[g >> 1];
        const float s0 = rsqrtf(fmaxf(fabsf(px - c.x) * inv_half, 1.0f) *
                                fmaxf(fabsf(py - c.y) * inv_half, 1.0f));
        const float s1 = rsqrtf(fmaxf(fabsf(px - c.z) * inv_half, 1.0f) *
                                fmaxf(fabsf(py - c.w) * inv_half, 1.0f));
        if (s0 < min_score) { min_score = s0; min_g = g; }
        if (s1 < min_score) { min_score = s1; min_g = g + 1; }
    }
    if (g < G) {
        const float2 c = ctr[g];
        const float s0 = rsqrtf(fmaxf(fabsf(px - c.x) * inv_half, 1.0f) *
                                fmaxf(fabsf(py - c.y) * inv_half, 1.0f));
        if (s0 < min_score) { min_score = s0; min_g = g; }
    }

    // zeros must be in L2 before any same-address atomic/patch
    asm volatile("s_waitcnt vmcnt(0)" ::: "memory");

    // --- phase 3: compacted gts: hit test, green atomicMax + best ---
    float* myout = out + (size_t)(b * P + p) * ROWF;
    float best_score = 0.0f; int best_g = 0;
    unsigned gm0 = 0u, gm1 = 0u, gm2 = 0u;
    for (int i = 0; i < ncomp; ++i) {
        const unsigned e = clist[i];
        const int gg = (int)(e & 0xFFu);
        const float4 A = boxA[gg];
        const float d1 = px - A.x, d2 = py - A.y, d3 = A.z - px, d4 = A.w - py;
        if (fminf(fminf(d1, d2), fminf(d3, d4)) >= 0.0f) {
            const int label = (int)((e >> 8) & 0x7Fu);
            if (e & 0x80000000u) {          // gray
                if (label < 32)      gm0 |= 1u << label;
                else if (label < 64) gm1 |= 1u << (label - 32);
                else                 gm2 |= 1u << (label - 64);
            } else {                         // green
                const float2 c = ctr[gg];
                const float s = rsqrtf(fmaxf(fabsf(px - c.x) * inv_half, 1.0f) *
                                       fmaxf(fabsf(py - c.y) * inv_half, 1.0f));
                atomicMax((int*)(myout + label), __float_as_int(s)); // s>0: int order == float order
                if (s > best_score) { best_score = s; best_g = gg; }
            }
        }
    }

    // green atomics must complete before gray -1 overrides (same addresses)
    asm volatile("s_waitcnt vmcnt(0)" ::: "memory");

    // --- phase 4: gray overrides + reg store (row p touched only by thread p) ---
    while (gm0) { const int c = __ffs(gm0) - 1; myout[c]      = -1.0f; gm0 &= gm0 - 1u; }
    while (gm1) { const int c = __ffs(gm1) - 1; myout[32 + c] = -1.0f; gm1 &= gm1 - 1u; }
    while (gm2) { const int c = __ffs(gm2) - 1; myout[64 + c] = -1.0f; gm2 &= gm2 - 1u; }

    const int sel = (best_score > 0.0f) ? best_g : min_g;
    const float4 A = boxA[sel];
    *(float4*)(myout + 80) = make_float4((px - A.x) * inv_up, (py - A.y) * inv_up,
                                         (A.z - px) * inv_up, (A.w - py) * inv_up);
}

extern "C" void kernel_launch(void* const* d_in, const int* in_sizes, int n_in,
                              void* d_out, int out_size, void* d_ws, size_t ws_size,
                              hipStream_t stream) {
    const float* gt_bboxes   = (const float*)d_in[0];
    const int*   gt_labels   = (const int*)d_in[1];
    const float* points      = (const float*)d_in[2];
    const float* reg_ranges  = (const float*)d_in[3];
    const float* gray_ranges = (const float*)d_in[4];
    const float* strides     = (const float*)d_in[5];
    float* out = (float*)d_out;

    const int P = in_sizes[5];            // strides has P elements
    const int B = out_size / (P * ROWF);  // out is (B,P,84)
    const int G = in_sizes[1] / B;        // gt_labels is (B,G)  (G<=128 assumed)

    dim3 grid(P / 64, B);
    dim3 block(64);
    const size_t shmem = (size_t)G * sizeof(float4)              // boxA
                       + (size_t)((G + 1) & ~1) * sizeof(float2) // ctr (16B-aligned base)
                       + (size_t)G * sizeof(unsigned);           // clist
    lfd_assign_kernel<<<grid, block, shmem, stream>>>(
        gt_bboxes, gt_labels, points, reg_ranges, gray_ranges, strides, out, G, P);
}